// Round 11
// baseline (150.756 us; speedup 1.0000x reference)
//
#include <hip/hip_runtime.h>
#include <hip/hip_bf16.h>
#include <stdint.h>

// Problem constants (fixed by setup_inputs)
#define NPTS   65536
#define MPTS   2048
#define NGRAPH 32

typedef short s16x8 __attribute__((ext_vector_type(8)));
typedef float f32x4 __attribute__((ext_vector_type(4)));

// ws layout (bytes)
#define FEATP_OFF 0u            // 4096 ptiles * 3 ktiles * 1024B = 12582912
#define W1P_OFF   12582912u     // 96*1024*2   = 196608
#define W2P_OFF   12779520u     // 1024*256*2  = 524288
#define SACC_OFF  13303808u     // 32*256*4    = 32768  (per-graph sum of h2)
#define POOLT_OFF 13336576u     // 32*9*4      = 1152
#define ZKEY_OFF  13337728u     // 32*2048*4   = 262144 (total 13599872 B)

#define PAD  128                // sentinel pad on each side of z-sorted array
#define ZN   (MPTS + 2 * PAD)   // 2304

__device__ __forceinline__ unsigned short f2bf(float f) {
  unsigned u = __float_as_uint(f);
  u = (u + 0x7FFFu + ((u >> 16) & 1u)) >> 16;   // RNE
  return (unsigned short)u;
}

// u32 compare-exchange: v_min_u32 + v_max_u32 (2 VALU, no vcc).
__device__ __forceinline__ void ce32(unsigned& a, unsigned& b) {
  unsigned lo = __builtin_elementwise_min(a, b);
  b = __builtin_elementwise_max(a, b);
  a = lo;
}

// Batcher odd-even mergesort, ascending, fully unrolled (N=8: 19 CEs).
template <int N>
__device__ __forceinline__ void sortN(unsigned* k) {
#pragma unroll
  for (int p = 1; p < N; p <<= 1)
#pragma unroll
    for (int q = p; q >= 1; q >>= 1)
#pragma unroll
      for (int j = q % p; j + q < N; j += 2 * q)
#pragma unroll
        for (int i = 0; i < q; ++i)
          if (i + j + q < N)
            if ((i + j) / (2 * p) == (i + j + q) / (2 * p))
              ce32(k[i + j], k[i + j + q]);
}

// r,b sorted asc. r <- lowest 8 of r ∪ b, sorted asc. 8 min + 12 CE.
__device__ __forceinline__ void mergelow8(unsigned r[8], const unsigned b[8]) {
#pragma unroll
  for (int i = 0; i < 8; ++i)
    r[i] = __builtin_elementwise_min(r[i], b[7 - i]);
#pragma unroll
  for (int d = 4; d >= 1; d >>= 1)
#pragma unroll
    for (int i = 0; i < 8; ++i)
      if ((i & d) == 0) ce32(r[i], r[i + d]);
}

// r,b sorted asc (16 each). r <- lowest 16, sorted. 16 min + 32 CE.
__device__ __forceinline__ void mergelow16(unsigned r[16], const unsigned b[16]) {
#pragma unroll
  for (int i = 0; i < 16; ++i)
    r[i] = __builtin_elementwise_min(r[i], b[15 - i]);
#pragma unroll
  for (int d = 8; d >= 1; d >>= 1)
#pragma unroll
    for (int i = 0; i < 16; ++i)
      if ((i & d) == 0) ce32(r[i], r[i + d]);
}

// ---------------------------------------------------------------------------
// Kernel 1 (prep): blocks 0..31 z-sort one graph each (hierarchical bitonic:
// shfl for j<=32, in-thread slots for j in {64,128}, LDS only for j>=256);
// blocks 32.. pack W1/W2 into MFMA fragment-linear bf16 tiles, zero sacc.
// ---------------------------------------------------------------------------
__global__ __launch_bounds__(512) void prep(
    const float* __restrict__ pos, const float* __restrict__ W1,
    const float* __restrict__ W2, unsigned* __restrict__ zkeysG,
    unsigned short* __restrict__ w1p, unsigned short* __restrict__ w2p,
    float* __restrict__ sacc)
{
  __shared__ unsigned sk[MPTS];
  int b = blockIdx.x;
  int tid = threadIdx.x;
  if (b < NGRAPH) {
    const float* gp = pos + (size_t)b * MPTS * 3;
    int w = tid >> 6, l = tid & 63;
    unsigned v[4];
#pragma unroll
    for (int s = 0; s < 4; ++s) {
      int i = w * 256 + s * 64 + l;
      unsigned u = __float_as_uint(gp[i * 3 + 2]);
      u ^= ((unsigned)(((int)u) >> 31)) | 0x80000000u;   // monotone fold
      v[s] = (u & 0xFFFFF800u) | (unsigned)i;
    }
#pragma unroll
    for (int kk = 1; kk <= 11; ++kk) {
      const int k2 = 1 << kk;
      // LDS stages: j in {1024, 512, 256} (cross-wave)
      if (k2 >= 512) {
        __syncthreads();                       // protect sk vs prior loads
#pragma unroll
        for (int s = 0; s < 4; ++s) sk[w * 256 + s * 64 + l] = v[s];
#pragma unroll
        for (int j = k2 >> 1; j >= 256; j >>= 1) {
          __syncthreads();
#pragma unroll
          for (int e = 0; e < 4; ++e) {
            int i = tid + (e << 9);
            int ix = i ^ j;
            if (ix > i) {
              unsigned a = sk[i], b2 = sk[ix];
              bool up = ((i & k2) == 0);
              unsigned lo = __builtin_elementwise_min(a, b2);
              unsigned hi = __builtin_elementwise_max(a, b2);
              sk[i] = up ? lo : hi;
              sk[ix] = up ? hi : lo;
            }
          }
        }
        __syncthreads();
#pragma unroll
        for (int s = 0; s < 4; ++s) v[s] = sk[w * 256 + s * 64 + l];
      }
      // in-thread slot stages: j = 128 (s^2), 64 (s^1)
#pragma unroll
      for (int j = 128; j >= 64; j >>= 1) {
        if (k2 > j) {
          int sd = j >> 6;
#pragma unroll
          for (int s = 0; s < 4; ++s) {
            int sp = s ^ sd;
            if (sp > s) {
              bool up = (((w * 256 + s * 64 + l) & k2) == 0);
              unsigned lo = __builtin_elementwise_min(v[s], v[sp]);
              unsigned hi = __builtin_elementwise_max(v[s], v[sp]);
              v[s] = up ? lo : hi;
              v[sp] = up ? hi : lo;
            }
          }
        }
      }
      // shfl stages: j = 32..1 (in-wave, no barriers)
#pragma unroll
      for (int j = 32; j >= 1; j >>= 1) {
        if (k2 > j) {
#pragma unroll
          for (int s = 0; s < 4; ++s) {
            unsigned p = __shfl_xor(v[s], j, 64);
            bool up = (((w * 256 + s * 64 + l) & k2) == 0);
            bool lower = ((l & j) == 0);
            v[s] = (lower == up) ? __builtin_elementwise_min(v[s], p)
                                 : __builtin_elementwise_max(v[s], p);
          }
        }
      }
    }
#pragma unroll
    for (int s = 0; s < 4; ++s)
      zkeysG[(b << 11) + w * 256 + s * 64 + l] = v[s];
  } else {
    int pid = (b - NGRAPH) * 512 + tid;
    if (pid < 98304) {                          // W1: 96 x 1024
      int k = pid >> 10, n = pid & 1023;
      int kt = k >> 5, h = (k >> 3) & 3, j = k & 7;
      int nt = n >> 4, cc = n & 15;
      w1p[((size_t)(kt * 64 + nt) * 64 + h * 16 + cc) * 8 + j] = f2bf(W1[pid]);
    } else if (pid < 98304 + 262144) {          // W2: 1024 x 256
      int t = pid - 98304;
      int k = t >> 8, n = t & 255;
      int kt = k >> 5, h = (k >> 3) & 3, j = k & 7;
      int nt = n >> 4, cc = n & 15;
      w2p[((size_t)(kt * 16 + nt) * 64 + h * 16 + cc) * 8 + j] = f2bf(W2[t]);
    } else if (pid < 360448 + 8192) {           // zero per-graph h2 sums
      sacc[pid - 360448] = 0.0f;
    }
  }
}

// ---------------------------------------------------------------------------
// Kernel 2 (v9): wave-shared z-window 16-NN + LOSSLESS selection skip.
// After computing the 16 candidate keys, vmin = min16(keys) (15 ops). If no
// lane has vmin < run[7], the keep-low-8 merge is a provable no-op for every
// lane (keys unique, all new > each lane's 8th-best) -> skip the 140-op
// sort/merge network and the B shuffle-reduce, wave-uniformly.
// Rest as round 10: spread rank-group map, tight pigeonhole bound
// B = max8(run[1]), inf-sentinel padding, frontier prefetch.
// ---------------------------------------------------------------------------
__global__ __launch_bounds__(512, 4) void knn_feat(
    const float* __restrict__ pos, const unsigned* __restrict__ zkeysG,
    unsigned short* __restrict__ featp)
{
  __shared__ float4 zq[ZN];
  const float INF = __uint_as_float(0x7F800000u);
  int g = blockIdx.x >> 5;
  const float* gp = pos + (size_t)g * MPTS * 3;
  for (int i = threadIdx.x; i < ZN; i += 512) {
    float4 v;
    if (i < PAD) v = make_float4(INF, INF, -INF, INF);          // left: z=-inf
    else if (i >= MPTS + PAD) v = make_float4(INF, INF, INF, INF);
    else {
      int o = (int)(zkeysG[(g << 11) + (i - PAD)] & 0x7FFu);
      float x = gp[o * 3], y = gp[o * 3 + 1], z = gp[o * 3 + 2];
      v = make_float4(x, y, z, fmaf(x, x, fmaf(y, y, z * z)));
    }
    zq[i] = v;
  }
  __syncthreads();

  int l = threadIdx.x & 63, w = threadIdx.x >> 6;
  int qv = l & 7, t = l >> 3;
  int R0 = ((w << 5) | (blockIdx.x & 31)) << 3;    // spread rank-group map
  int R = R0 + qv;                                 // this lane's query rank
  float4 c = zq[R + PAD];
  float cs = c.w, cz = c.z;
  float zc = 0.5f * (zq[R0 + PAD].z + zq[R0 + PAD + 7].z);   // wave z center

  unsigned run[8];
#pragma unroll
  for (int i = 0; i < 8; ++i) run[i] = 0xFFFFFFFFu;
  unsigned B = 0xFFFFFFFFu;                        // per-query d16 upper bound

  int LO = R0 + PAD, HI = R0 + PAD;                // scanned = [LO, HI)
  float zl = zq[LO - 1].z, zr = zq[HI].z;          // frontier (prefetched)

  for (int step = 0; step < 18; ++step) {
    bool canL = (LO >= PAD), canR = (HI + PAD <= ZN);
    unsigned thr = (B > 0xFFFEFFFFu) ? 0xFFFFFFFFu : B + 0x10000u;
    float dl = cz - zl, dr = zr - cz;
    bool doneL = !canL || ((__float_as_uint(dl * dl) & 0xFFFFF800u) > thr);
    bool doneR = !canR || ((__float_as_uint(dr * dr) & 0xFFFFF800u) > thr);
    if (__all(doneL && doneR)) break;

    bool goR = canR && (!canL || ((zr - zc) <= (zc - zl)));    // uniform
    int base = goR ? HI : LO - PAD;
    if (goR) HI += PAD; else LO -= PAD;

    // prefetch next frontier (latency hides under the candidate block)
    zl = (LO >= 1) ? zq[LO - 1].z : -INF;
    zr = (HI < ZN) ? zq[HI].z : INF;

    int bt = base + t;
    unsigned k[16];
#pragma unroll
    for (int i = 0; i < 16; ++i) {
      int p = bt + (i << 3);
      float4 P = zq[p];
      float dot = fmaf(c.x, P.x, fmaf(c.y, P.y, c.z * P.z));
      float d2 = fmaf(-2.0f, dot, cs + P.w);       // == 0 exactly for self
      k[i] = (__float_as_uint(d2) & 0xFFFFF800u) |
             ((unsigned)(p - PAD) & 0x7FFu);       // v_bfi pattern
    }

    // lossless skip: if no lane's best new key beats its 8th-best, the
    // merge cannot change run for any lane (keys are unique).
    unsigned vmin = k[0];
#pragma unroll
    for (int i = 1; i < 16; ++i) vmin = __builtin_elementwise_min(vmin, k[i]);
    if (__any(vmin < run[7])) {
      sortN<8>(k); sortN<8>(k + 8);
      mergelow8(k, k + 8);        // k[0..7] = sorted lowest 8 of this batch
      mergelow8(run, k);

      // tighten B: per-query max of run[1] over the 8 segment-threads
      unsigned bb = run[1];
      bb = __builtin_elementwise_max(bb, (unsigned)__shfl_xor(bb, 8, 64));
      bb = __builtin_elementwise_max(bb, (unsigned)__shfl_xor(bb, 16, 64));
      bb = __builtin_elementwise_max(bb, (unsigned)__shfl_xor(bb, 32, 64));
      B = bb;
    }
  }

  // cross-thread reduction over the 8 segment-threads of this query
  // (threads of one query differ in lane bits 3,4,5).
  unsigned t16[16];
  {
    unsigned oth[8];
#pragma unroll
    for (int i = 0; i < 8; ++i) oth[i] = __shfl_xor(run[i], 8, 64);
#pragma unroll
    for (int i = 0; i < 8; ++i) {
      unsigned a = run[i], x = oth[7 - i];
      t16[i]     = __builtin_elementwise_min(a, x);
      t16[i + 8] = __builtin_elementwise_max(a, x);
    }
#pragma unroll
    for (int d = 4; d >= 1; d >>= 1)
#pragma unroll
      for (int i = 0; i < 16; ++i)
        if ((i & d) == 0) ce32(t16[i], t16[i + d]);   // stays within halves
  }
#pragma unroll
  for (int m = 16; m <= 32; m <<= 1) {
    unsigned o2[16];
#pragma unroll
    for (int i = 0; i < 16; ++i) o2[i] = __shfl_xor(t16[i], m, 64);
    mergelow16(t16, o2);
  }

  // feature emission: lanes t==0 (l = 0..7), consecutive z-ranks -> coalesced
  if (t == 0) {
    float nx[16], ny[16], nz[16];
#pragma unroll
    for (int i = 0; i < 16; ++i) {
      int rk = (int)(t16[i] & 0x7FFu);
      float4 p = zq[rk + PAD];
      nx[i] = p.x; ny[i] = p.y; nz[i] = p.z;
    }
    int n = g * MPTS + R;                        // z-rank order (mean-invariant)
    unsigned short* op = featp + (size_t)(n >> 4) * 1536 + (size_t)(n & 15) * 8;
#pragma unroll
    for (int kt = 0; kt < 3; ++kt) {
#pragma unroll
      for (int h = 0; h < 4; ++h) {
        s16x8 v;
#pragma unroll
        for (int j = 0; j < 8; ++j) {
          int f = kt * 32 + h * 8 + j;
          int kn = f / 6, comp = f % 6;        // compile-time after unroll
          float val;
          if      (comp == 0) val = c.x;
          else if (comp == 1) val = c.y;
          else if (comp == 2) val = c.z;
          else if (comp == 3) val = c.x - nx[kn];
          else if (comp == 4) val = c.y - ny[kn];
          else                val = c.z - nz[kn];
          v[j] = (short)f2bf(val);
        }
        *(s16x8*)(op + kt * 512 + h * 128) = v;
      }
    }
  }
}

// ---------------------------------------------------------------------------
// Kernel 3 (v4): fused MLP. As round 10 plus:
//  - __launch_bounds__(512,3): 3 blocks/CU (LDS 3x34816=102KB), +50% waves
//    to hide the barrier drain (round-4 lesson: this kernel is latency-bound).
//  - h1 pack via scalar __float2bfloat16 cast (compiler fuses to cvt_pk).
// ---------------------------------------------------------------------------
__global__ __launch_bounds__(512, 3) void mlp_fused(
    const unsigned short* __restrict__ featp,
    const unsigned short* __restrict__ w1p,
    const unsigned short* __restrict__ w2p,
    const float* __restrict__ b1, const float* __restrict__ b2,
    float* __restrict__ sacc)
{
  __shared__ unsigned short h1c[2][64][136];  // 2 x 17408 B, rows 16B-aligned

  int tid = threadIdx.x;
  int w = tid >> 6, lane = tid & 63;
  int b = blockIdx.x;
  int g = b >> 5;                             // 32 blocks per graph
  int ks = lane >> 4;                         // k-slot / C row-group
  int cl = lane & 15;

  // persistent A fragments: all 4 m-tiles x 3 k-tiles (48 VGPR)
  s16x8 a1[4][3];
#pragma unroll
  for (int m = 0; m < 4; ++m) {
    const unsigned short* ap = featp + (size_t)(b * 4 + m) * 1536 + (size_t)lane * 8;
#pragma unroll
    for (int kt = 0; kt < 3; ++kt) a1[m][kt] = *(const s16x8*)(ap + kt * 512);
  }

  f32x4 acc2[4][2];                           // 4 m-tiles x 2 n2-tiles
#pragma unroll
  for (int m = 0; m < 4; ++m) {
    acc2[m][0] = (f32x4){0, 0, 0, 0};
    acc2[m][1] = (f32x4){0, 0, 0, 0};
  }

  // B1 fragments for chunk 0 (nt = w)
  s16x8 b1f[3];
#pragma unroll
  for (int kt = 0; kt < 3; ++kt)
    b1f[kt] = *(const s16x8*)(w1p + ((size_t)(kt * 64 + w) * 64 + lane) * 8);

  for (int c = 0; c < 8; ++c) {
    int buf = c & 1;
    // this chunk's B2 fragments (overlap with GEMM1 compute)
    s16x8 b2f[8];
#pragma unroll
    for (int kt2 = 0; kt2 < 4; ++kt2)
#pragma unroll
      for (int j = 0; j < 2; ++j)
        b2f[kt2 * 2 + j] = *(const s16x8*)(
            w2p + ((size_t)((c * 4 + kt2) * 16 + (w * 2 + j)) * 64 + lane) * 8);

    // ---- GEMM1: h1 cols of tile nt1 = c*8 + w, all 4 m-tiles ----
    float bias1 = b1[(c * 8 + w) * 16 + cl];
#pragma unroll
    for (int m = 0; m < 4; ++m) {
      f32x4 acc1 = (f32x4){0, 0, 0, 0};
#pragma unroll
      for (int kt = 0; kt < 3; ++kt)
        acc1 = __builtin_amdgcn_mfma_f32_16x16x32_bf16(a1[m][kt], b1f[kt], acc1, 0, 0, 0);
#pragma unroll
      for (int r = 0; r < 4; ++r) {
        float v = fmaxf(acc1[r] + bias1, 0.0f);
        __hip_bfloat16 hv = __float2bfloat16(v);
        h1c[buf][m * 16 + ks * 4 + r][w * 16 + cl] =
            *reinterpret_cast<unsigned short*>(&hv);
      }
    }

    // next chunk's B1 fragments (in flight across the barrier)
    if (c < 7) {
#pragma unroll
      for (int kt = 0; kt < 3; ++kt)
        b1f[kt] = *(const s16x8*)(
            w1p + ((size_t)(kt * 64 + (c + 1) * 8 + w) * 64 + lane) * 8);
    }
    __syncthreads();                          // ONE barrier per chunk

    // ---- GEMM2 partial: nt2 in {2w, 2w+1}, all 4 m, K-chunk c ----
#pragma unroll
    for (int kt2 = 0; kt2 < 4; ++kt2) {
      s16x8 afr[4];
#pragma unroll
      for (int m = 0; m < 4; ++m)
        afr[m] = *(const s16x8*)&h1c[buf][m * 16 + cl][kt2 * 32 + ks * 8];
#pragma unroll
      for (int j = 0; j < 2; ++j)
#pragma unroll
        for (int m = 0; m < 4; ++m)
          acc2[m][j] = __builtin_amdgcn_mfma_f32_16x16x32_bf16(
              afr[m], b2f[kt2 * 2 + j], acc2[m][j], 0, 0, 0);
    }
  }

  // ---- h2 = relu(acc2 + b2); sum over this block's 64 points ----
  float sj0 = 0.0f, sj1 = 0.0f;
  {
    float bias20 = b2[(2 * w + 0) * 16 + cl];
    float bias21 = b2[(2 * w + 1) * 16 + cl];
#pragma unroll
    for (int m = 0; m < 4; ++m)
#pragma unroll
      for (int r = 0; r < 4; ++r) {
        float v0 = acc2[m][0][r] + bias20;
        float v1 = acc2[m][1][r] + bias21;
        sj0 += v0 > 0.0f ? v0 : 0.0f;
        sj1 += v1 > 0.0f ? v1 : 0.0f;
      }
  }
#pragma unroll
  for (int m = 16; m <= 32; m <<= 1) {
    sj0 += __shfl_xor(sj0, m, 64);
    sj1 += __shfl_xor(sj1, m, 64);
  }
  if (ks == 0) {
    atomicAdd(&sacc[g * 256 + (2 * w + 0) * 16 + cl], sj0);
    atomicAdd(&sacc[g * 256 + (2 * w + 1) * 16 + cl], sj1);
  }
}

// ---------------------------------------------------------------------------
// Kernel 4: pooledT[g][o] = (sacc[g] . W3[:,o]) / 2048 + b3[o]   (fp32)
// ---------------------------------------------------------------------------
__global__ __launch_bounds__(96) void pool_w3(
    const float* __restrict__ sacc, const float* __restrict__ W3,
    const float* __restrict__ b3, float* __restrict__ pooledT)
{
  int gid = blockIdx.x * 96 + threadIdx.x;
  if (gid >= NGRAPH * 9) return;
  int g = gid / 9, o = gid % 9;
  float acc = 0.0f;
  const float* sp = sacc + g * 256;
#pragma unroll 8
  for (int k = 0; k < 256; ++k) acc = fmaf(sp[k], W3[k * 9 + o], acc);
  pooledT[gid] = fmaf(acc, 1.0f / (float)MPTS, b3[o]);
}

// ---------------------------------------------------------------------------
// Kernel 5: out[n,k] = sum_d pos[n,d] * pooledT[batch[n]][d*3+k]
// ---------------------------------------------------------------------------
__global__ __launch_bounds__(256) void finalize(
    const float* __restrict__ pos, const int* __restrict__ batch,
    const float* __restrict__ pooledT, float* __restrict__ out)
{
  int n = blockIdx.x * 256 + threadIdx.x;
  if (n >= NPTS) return;
  int bb = batch[n];
  float px = pos[n * 3], py = pos[n * 3 + 1], pz = pos[n * 3 + 2];
  const float* P = pooledT + bb * 9;
#pragma unroll
  for (int k2 = 0; k2 < 3; ++k2)
    out[n * 3 + k2] = fmaf(px, P[k2], fmaf(py, P[3 + k2], pz * P[6 + k2]));
}

extern "C" void kernel_launch(void* const* d_in, const int* in_sizes, int n_in,
                              void* d_out, int out_size, void* d_ws, size_t ws_size,
                              hipStream_t stream) {
  const float* pos  = (const float*)d_in[0];
  const int*   batch = (const int*)d_in[1];
  const float* W1 = (const float*)d_in[3];
  const float* b1 = (const float*)d_in[4];
  const float* W2 = (const float*)d_in[5];
  const float* b2 = (const float*)d_in[6];
  const float* W3 = (const float*)d_in[7];
  const float* b3 = (const float*)d_in[8];

  char* ws = (char*)d_ws;                      // needs ~13.0 MiB
  unsigned short* featp = (unsigned short*)(ws + FEATP_OFF);
  unsigned short* w1p   = (unsigned short*)(ws + W1P_OFF);
  unsigned short* w2p   = (unsigned short*)(ws + W2P_OFF);
  float*          sacc  = (float*)(ws + SACC_OFF);
  float*          pooledT = (float*)(ws + POOLT_OFF);
  unsigned*       zkeysG = (unsigned*)(ws + ZKEY_OFF);
  float*          out = (float*)d_out;

  prep<<<dim3(752), dim3(512), 0, stream>>>(pos, W1, W2, zkeysG, w1p, w2p, sacc);
  knn_feat<<<dim3(1024), dim3(512), 0, stream>>>(pos, zkeysG, featp);
  mlp_fused<<<dim3(1024), dim3(512), 0, stream>>>(featp, w1p, w2p, b1, b2, sacc);
  pool_w3<<<dim3(3), dim3(96), 0, stream>>>(sacc, W3, b3, pooledT);
  finalize<<<dim3(256), dim3(256), 0, stream>>>(pos, batch, pooledT, out);
}

// Round 12
// 135.478 us; speedup vs baseline: 1.1128x; 1.1128x over previous
//
#include <hip/hip_runtime.h>
#include <stdint.h>

// Problem constants (fixed by setup_inputs)
#define NPTS   65536
#define MPTS   2048
#define NGRAPH 32

typedef short s16x8 __attribute__((ext_vector_type(8)));
typedef float f32x4 __attribute__((ext_vector_type(4)));

// ws layout (bytes)
#define FEATP_OFF 0u            // 4096 ptiles * 3 ktiles * 1024B = 12582912
#define W1P_OFF   12582912u     // 96*1024*2   = 196608
#define W2P_OFF   12779520u     // 1024*256*2  = 524288
#define SACC_OFF  13303808u     // 32*256*4    = 32768  (per-graph sum of h2)
#define POOLT_OFF 13336576u     // 32*9*4      = 1152
#define ZKEY_OFF  13337728u     // 32*2048*4   = 262144 (total 13599872 B)

#define PAD  128                // sentinel pad on each side of z-sorted array
#define ZN   (MPTS + 2 * PAD)   // 2304

__device__ __forceinline__ unsigned short f2bf(float f) {
  unsigned u = __float_as_uint(f);
  u = (u + 0x7FFFu + ((u >> 16) & 1u)) >> 16;   // RNE
  return (unsigned short)u;
}

// u32 compare-exchange: v_min_u32 + v_max_u32 (2 VALU, no vcc).
__device__ __forceinline__ void ce32(unsigned& a, unsigned& b) {
  unsigned lo = __builtin_elementwise_min(a, b);
  b = __builtin_elementwise_max(a, b);
  a = lo;
}

// Batcher odd-even mergesort, ascending, fully unrolled (N=8: 19 CEs).
template <int N>
__device__ __forceinline__ void sortN(unsigned* k) {
#pragma unroll
  for (int p = 1; p < N; p <<= 1)
#pragma unroll
    for (int q = p; q >= 1; q >>= 1)
#pragma unroll
      for (int j = q % p; j + q < N; j += 2 * q)
#pragma unroll
        for (int i = 0; i < q; ++i)
          if (i + j + q < N)
            if ((i + j) / (2 * p) == (i + j + q) / (2 * p))
              ce32(k[i + j], k[i + j + q]);
}

// r,b sorted asc. r <- lowest 8 of r ∪ b, sorted asc. 8 min + 12 CE.
__device__ __forceinline__ void mergelow8(unsigned r[8], const unsigned b[8]) {
#pragma unroll
  for (int i = 0; i < 8; ++i)
    r[i] = __builtin_elementwise_min(r[i], b[7 - i]);
#pragma unroll
  for (int d = 4; d >= 1; d >>= 1)
#pragma unroll
    for (int i = 0; i < 8; ++i)
      if ((i & d) == 0) ce32(r[i], r[i + d]);
}

// r,b sorted asc (16 each). r <- lowest 16, sorted. 16 min + 32 CE.
__device__ __forceinline__ void mergelow16(unsigned r[16], const unsigned b[16]) {
#pragma unroll
  for (int i = 0; i < 16; ++i)
    r[i] = __builtin_elementwise_min(r[i], b[15 - i]);
#pragma unroll
  for (int d = 8; d >= 1; d >>= 1)
#pragma unroll
    for (int i = 0; i < 16; ++i)
      if ((i & d) == 0) ce32(r[i], r[i + d]);
}

// ---------------------------------------------------------------------------
// Kernel 1 (prep): blocks 0..31 z-sort one graph each (hierarchical bitonic:
// shfl for j<=32, in-thread slots for j in {64,128}, LDS only for j>=256);
// blocks 32.. pack W1/W2 into MFMA fragment-linear bf16 tiles, zero sacc.
// ---------------------------------------------------------------------------
__global__ __launch_bounds__(512) void prep(
    const float* __restrict__ pos, const float* __restrict__ W1,
    const float* __restrict__ W2, unsigned* __restrict__ zkeysG,
    unsigned short* __restrict__ w1p, unsigned short* __restrict__ w2p,
    float* __restrict__ sacc)
{
  __shared__ unsigned sk[MPTS];
  int b = blockIdx.x;
  int tid = threadIdx.x;
  if (b < NGRAPH) {
    const float* gp = pos + (size_t)b * MPTS * 3;
    int w = tid >> 6, l = tid & 63;
    unsigned v[4];
#pragma unroll
    for (int s = 0; s < 4; ++s) {
      int i = w * 256 + s * 64 + l;
      unsigned u = __float_as_uint(gp[i * 3 + 2]);
      u ^= ((unsigned)(((int)u) >> 31)) | 0x80000000u;   // monotone fold
      v[s] = (u & 0xFFFFF800u) | (unsigned)i;
    }
#pragma unroll
    for (int kk = 1; kk <= 11; ++kk) {
      const int k2 = 1 << kk;
      // LDS stages: j in {1024, 512, 256} (cross-wave)
      if (k2 >= 512) {
        __syncthreads();                       // protect sk vs prior loads
#pragma unroll
        for (int s = 0; s < 4; ++s) sk[w * 256 + s * 64 + l] = v[s];
#pragma unroll
        for (int j = k2 >> 1; j >= 256; j >>= 1) {
          __syncthreads();
#pragma unroll
          for (int e = 0; e < 4; ++e) {
            int i = tid + (e << 9);
            int ix = i ^ j;
            if (ix > i) {
              unsigned a = sk[i], b2 = sk[ix];
              bool up = ((i & k2) == 0);
              unsigned lo = __builtin_elementwise_min(a, b2);
              unsigned hi = __builtin_elementwise_max(a, b2);
              sk[i] = up ? lo : hi;
              sk[ix] = up ? hi : lo;
            }
          }
        }
        __syncthreads();
#pragma unroll
        for (int s = 0; s < 4; ++s) v[s] = sk[w * 256 + s * 64 + l];
      }
      // in-thread slot stages: j = 128 (s^2), 64 (s^1)
#pragma unroll
      for (int j = 128; j >= 64; j >>= 1) {
        if (k2 > j) {
          int sd = j >> 6;
#pragma unroll
          for (int s = 0; s < 4; ++s) {
            int sp = s ^ sd;
            if (sp > s) {
              bool up = (((w * 256 + s * 64 + l) & k2) == 0);
              unsigned lo = __builtin_elementwise_min(v[s], v[sp]);
              unsigned hi = __builtin_elementwise_max(v[s], v[sp]);
              v[s] = up ? lo : hi;
              v[sp] = up ? hi : lo;
            }
          }
        }
      }
      // shfl stages: j = 32..1 (in-wave, no barriers)
#pragma unroll
      for (int j = 32; j >= 1; j >>= 1) {
        if (k2 > j) {
#pragma unroll
          for (int s = 0; s < 4; ++s) {
            unsigned p = __shfl_xor(v[s], j, 64);
            bool up = (((w * 256 + s * 64 + l) & k2) == 0);
            bool lower = ((l & j) == 0);
            v[s] = (lower == up) ? __builtin_elementwise_min(v[s], p)
                                 : __builtin_elementwise_max(v[s], p);
          }
        }
      }
    }
#pragma unroll
    for (int s = 0; s < 4; ++s)
      zkeysG[(b << 11) + w * 256 + s * 64 + l] = v[s];
  } else {
    int pid = (b - NGRAPH) * 512 + tid;
    if (pid < 98304) {                          // W1: 96 x 1024
      int k = pid >> 10, n = pid & 1023;
      int kt = k >> 5, h = (k >> 3) & 3, j = k & 7;
      int nt = n >> 4, cc = n & 15;
      w1p[((size_t)(kt * 64 + nt) * 64 + h * 16 + cc) * 8 + j] = f2bf(W1[pid]);
    } else if (pid < 98304 + 262144) {          // W2: 1024 x 256
      int t = pid - 98304;
      int k = t >> 8, n = t & 255;
      int kt = k >> 5, h = (k >> 3) & 3, j = k & 7;
      int nt = n >> 4, cc = n & 15;
      w2p[((size_t)(kt * 16 + nt) * 64 + h * 16 + cc) * 8 + j] = f2bf(W2[t]);
    } else if (pid < 360448 + 8192) {           // zero per-graph h2 sums
      sacc[pid - 360448] = 0.0f;
    }
  }
}

// ---------------------------------------------------------------------------
// Kernel 2 (v9, unchanged from round 11): wave-shared z-window 16-NN with
// lossless selection skip, tight pigeonhole bound, sentinel padding.
// ---------------------------------------------------------------------------
__global__ __launch_bounds__(512, 4) void knn_feat(
    const float* __restrict__ pos, const unsigned* __restrict__ zkeysG,
    unsigned short* __restrict__ featp)
{
  __shared__ float4 zq[ZN];
  const float INF = __uint_as_float(0x7F800000u);
  int g = blockIdx.x >> 5;
  const float* gp = pos + (size_t)g * MPTS * 3;
  for (int i = threadIdx.x; i < ZN; i += 512) {
    float4 v;
    if (i < PAD) v = make_float4(INF, INF, -INF, INF);          // left: z=-inf
    else if (i >= MPTS + PAD) v = make_float4(INF, INF, INF, INF);
    else {
      int o = (int)(zkeysG[(g << 11) + (i - PAD)] & 0x7FFu);
      float x = gp[o * 3], y = gp[o * 3 + 1], z = gp[o * 3 + 2];
      v = make_float4(x, y, z, fmaf(x, x, fmaf(y, y, z * z)));
    }
    zq[i] = v;
  }
  __syncthreads();

  int l = threadIdx.x & 63, w = threadIdx.x >> 6;
  int qv = l & 7, t = l >> 3;
  int R0 = ((w << 5) | (blockIdx.x & 31)) << 3;    // spread rank-group map
  int R = R0 + qv;                                 // this lane's query rank
  float4 c = zq[R + PAD];
  float cs = c.w, cz = c.z;
  float zc = 0.5f * (zq[R0 + PAD].z + zq[R0 + PAD + 7].z);   // wave z center

  unsigned run[8];
#pragma unroll
  for (int i = 0; i < 8; ++i) run[i] = 0xFFFFFFFFu;
  unsigned B = 0xFFFFFFFFu;                        // per-query d16 upper bound

  int LO = R0 + PAD, HI = R0 + PAD;                // scanned = [LO, HI)
  float zl = zq[LO - 1].z, zr = zq[HI].z;          // frontier (prefetched)

  for (int step = 0; step < 18; ++step) {
    bool canL = (LO >= PAD), canR = (HI + PAD <= ZN);
    unsigned thr = (B > 0xFFFEFFFFu) ? 0xFFFFFFFFu : B + 0x10000u;
    float dl = cz - zl, dr = zr - cz;
    bool doneL = !canL || ((__float_as_uint(dl * dl) & 0xFFFFF800u) > thr);
    bool doneR = !canR || ((__float_as_uint(dr * dr) & 0xFFFFF800u) > thr);
    if (__all(doneL && doneR)) break;

    bool goR = canR && (!canL || ((zr - zc) <= (zc - zl)));    // uniform
    int base = goR ? HI : LO - PAD;
    if (goR) HI += PAD; else LO -= PAD;

    // prefetch next frontier (latency hides under the candidate block)
    zl = (LO >= 1) ? zq[LO - 1].z : -INF;
    zr = (HI < ZN) ? zq[HI].z : INF;

    int bt = base + t;
    unsigned k[16];
#pragma unroll
    for (int i = 0; i < 16; ++i) {
      int p = bt + (i << 3);
      float4 P = zq[p];
      float dot = fmaf(c.x, P.x, fmaf(c.y, P.y, c.z * P.z));
      float d2 = fmaf(-2.0f, dot, cs + P.w);       // == 0 exactly for self
      k[i] = (__float_as_uint(d2) & 0xFFFFF800u) |
             ((unsigned)(p - PAD) & 0x7FFu);       // v_bfi pattern
    }

    // lossless skip: if no lane's best new key beats its 8th-best, the
    // merge cannot change run for any lane (keys are unique).
    unsigned vmin = k[0];
#pragma unroll
    for (int i = 1; i < 16; ++i) vmin = __builtin_elementwise_min(vmin, k[i]);
    if (__any(vmin < run[7])) {
      sortN<8>(k); sortN<8>(k + 8);
      mergelow8(k, k + 8);        // k[0..7] = sorted lowest 8 of this batch
      mergelow8(run, k);

      // tighten B: per-query max of run[1] over the 8 segment-threads
      unsigned bb = run[1];
      bb = __builtin_elementwise_max(bb, (unsigned)__shfl_xor(bb, 8, 64));
      bb = __builtin_elementwise_max(bb, (unsigned)__shfl_xor(bb, 16, 64));
      bb = __builtin_elementwise_max(bb, (unsigned)__shfl_xor(bb, 32, 64));
      B = bb;
    }
  }

  // cross-thread reduction over the 8 segment-threads of this query
  unsigned t16[16];
  {
    unsigned oth[8];
#pragma unroll
    for (int i = 0; i < 8; ++i) oth[i] = __shfl_xor(run[i], 8, 64);
#pragma unroll
    for (int i = 0; i < 8; ++i) {
      unsigned a = run[i], x = oth[7 - i];
      t16[i]     = __builtin_elementwise_min(a, x);
      t16[i + 8] = __builtin_elementwise_max(a, x);
    }
#pragma unroll
    for (int d = 4; d >= 1; d >>= 1)
#pragma unroll
      for (int i = 0; i < 16; ++i)
        if ((i & d) == 0) ce32(t16[i], t16[i + d]);   // stays within halves
  }
#pragma unroll
  for (int m = 16; m <= 32; m <<= 1) {
    unsigned o2[16];
#pragma unroll
    for (int i = 0; i < 16; ++i) o2[i] = __shfl_xor(t16[i], m, 64);
    mergelow16(t16, o2);
  }

  // feature emission: lanes t==0 (l = 0..7), consecutive z-ranks -> coalesced
  if (t == 0) {
    float nx[16], ny[16], nz[16];
#pragma unroll
    for (int i = 0; i < 16; ++i) {
      int rk = (int)(t16[i] & 0x7FFu);
      float4 p = zq[rk + PAD];
      nx[i] = p.x; ny[i] = p.y; nz[i] = p.z;
    }
    int n = g * MPTS + R;                        // z-rank order (mean-invariant)
    unsigned short* op = featp + (size_t)(n >> 4) * 1536 + (size_t)(n & 15) * 8;
#pragma unroll
    for (int kt = 0; kt < 3; ++kt) {
#pragma unroll
      for (int h = 0; h < 4; ++h) {
        s16x8 v;
#pragma unroll
        for (int j = 0; j < 8; ++j) {
          int f = kt * 32 + h * 8 + j;
          int kn = f / 6, comp = f % 6;        // compile-time after unroll
          float val;
          if      (comp == 0) val = c.x;
          else if (comp == 1) val = c.y;
          else if (comp == 2) val = c.z;
          else if (comp == 3) val = c.x - nx[kn];
          else if (comp == 4) val = c.y - ny[kn];
          else                val = c.z - nz[kn];
          v[j] = (short)f2bf(val);
        }
        *(s16x8*)(op + kt * 512 + h * 128) = v;
      }
    }
  }
}

// --- mlp helpers: C-array references so everything inlines to registers ----
__device__ __forceinline__ void load_b1(s16x8 (&dst)[3],
    const unsigned short* __restrict__ w1p, int nt, int lane) {
#pragma unroll
  for (int kt = 0; kt < 3; ++kt)
    dst[kt] = *(const s16x8*)(w1p + ((size_t)(kt * 64 + nt) * 64 + lane) * 8);
}

__device__ __forceinline__ void load_b2(s16x8 (&dst)[8],
    const unsigned short* __restrict__ w2p, int c, int w, int lane) {
#pragma unroll
  for (int kt2 = 0; kt2 < 4; ++kt2)
#pragma unroll
    for (int j = 0; j < 2; ++j)
      dst[kt2 * 2 + j] = *(const s16x8*)(
          w2p + ((size_t)((c * 4 + kt2) * 16 + (w * 2 + j)) * 64 + lane) * 8);
}

__device__ __forceinline__ void gemm1_step(const s16x8 (&a1)[4][3],
    const s16x8 (&b1f)[3], float bias1,
    unsigned short (*h1buf)[136], int w, int cl, int ks) {
#pragma unroll
  for (int m = 0; m < 4; ++m) {
    f32x4 acc1 = (f32x4){0, 0, 0, 0};
#pragma unroll
    for (int kt = 0; kt < 3; ++kt)
      acc1 = __builtin_amdgcn_mfma_f32_16x16x32_bf16(a1[m][kt], b1f[kt], acc1, 0, 0, 0);
#pragma unroll
    for (int r = 0; r < 4; ++r) {
      float v = acc1[r] + bias1;
      v = v > 0.0f ? v : 0.0f;
      h1buf[m * 16 + ks * 4 + r][w * 16 + cl] = f2bf(v);
    }
  }
}

__device__ __forceinline__ void gemm2_step(const s16x8 (&b2f)[8],
    f32x4 (&acc2)[4][2], const unsigned short (*h1buf)[136], int cl, int ks) {
#pragma unroll
  for (int kt2 = 0; kt2 < 4; ++kt2) {
    s16x8 afr[4];
#pragma unroll
    for (int m = 0; m < 4; ++m)
      afr[m] = *(const s16x8*)&h1buf[m * 16 + cl][kt2 * 32 + ks * 8];
#pragma unroll
    for (int j = 0; j < 2; ++j)
#pragma unroll
      for (int m = 0; m < 4; ++m)
        acc2[m][j] = __builtin_amdgcn_mfma_f32_16x16x32_bf16(
            afr[m], b2f[kt2 * 2 + j], acc2[m][j], 0, 0, 0);
  }
}

// ---------------------------------------------------------------------------
// Kernel 3 (v5): fused MLP. Round-10 structure (512,2 — no spill) plus a
// chunk-ahead B2 ping-pong: b2(c+1) is issued right AFTER barrier(c) and
// consumed after barrier(c+1), so it is in flight across GEMM2(c)+GEMM1(c+1)
// (~600 cyc) — the vmcnt(0) drain at each barrier then completes already-
// landed loads instead of stalling. bias1 loads hoisted to the prologue.
// ---------------------------------------------------------------------------
__global__ __launch_bounds__(512, 2) void mlp_fused(
    const unsigned short* __restrict__ featp,
    const unsigned short* __restrict__ w1p,
    const unsigned short* __restrict__ w2p,
    const float* __restrict__ b1, const float* __restrict__ b2,
    float* __restrict__ sacc)
{
  __shared__ unsigned short h1c[2][64][136];  // 2 x 17408 B, rows 16B-aligned

  int tid = threadIdx.x;
  int w = tid >> 6, lane = tid & 63;
  int b = blockIdx.x;
  int g = b >> 5;                             // 32 blocks per graph
  int ks = lane >> 4;                         // k-slot / C row-group
  int cl = lane & 15;

  // persistent A fragments: all 4 m-tiles x 3 k-tiles (48 VGPR)
  s16x8 a1[4][3];
#pragma unroll
  for (int m = 0; m < 4; ++m) {
    const unsigned short* ap = featp + (size_t)(b * 4 + m) * 1536 + (size_t)lane * 8;
#pragma unroll
    for (int kt = 0; kt < 3; ++kt) a1[m][kt] = *(const s16x8*)(ap + kt * 512);
  }

  f32x4 acc2[4][2];                           // 4 m-tiles x 2 n2-tiles
#pragma unroll
  for (int m = 0; m < 4; ++m) {
    acc2[m][0] = (f32x4){0, 0, 0, 0};
    acc2[m][1] = (f32x4){0, 0, 0, 0};
  }

  // all 8 chunk biases up front (8 VGPR)
  float bias1v[8];
#pragma unroll
  for (int c = 0; c < 8; ++c) bias1v[c] = b1[(c * 8 + w) * 16 + cl];

  s16x8 b1f[3];
  load_b1(b1f, w1p, w, lane);                 // chunk 0: nt = w
  s16x8 b2a[8], b2b[8];
  load_b2(b2a, w2p, 0, w, lane);              // chunk 0 B2

#pragma unroll
  for (int cc = 0; cc < 8; cc += 2) {
    // ---- even chunk cc -> buf 0 ----
    gemm1_step(a1, b1f, bias1v[cc], h1c[0], w, cl, ks);
    load_b1(b1f, w1p, (cc + 1) * 8 + w, lane);          // b1 for cc+1
    __syncthreads();
    load_b2(b2b, w2p, cc + 1, w, lane);                 // issue early: lands
    gemm2_step(b2a, acc2, h1c[0], cl, ks);              //   during these MFMAs

    // ---- odd chunk cc+1 -> buf 1 ----
    gemm1_step(a1, b1f, bias1v[cc + 1], h1c[1], w, cl, ks);
    if (cc + 2 < 8) load_b1(b1f, w1p, (cc + 2) * 8 + w, lane);
    __syncthreads();
    if (cc + 2 < 8) load_b2(b2a, w2p, cc + 2, w, lane);
    gemm2_step(b2b, acc2, h1c[1], cl, ks);
  }

  // ---- h2 = relu(acc2 + b2); sum over this block's 64 points ----
  float sj0 = 0.0f, sj1 = 0.0f;
  {
    float bias20 = b2[(2 * w + 0) * 16 + cl];
    float bias21 = b2[(2 * w + 1) * 16 + cl];
#pragma unroll
    for (int m = 0; m < 4; ++m)
#pragma unroll
      for (int r = 0; r < 4; ++r) {
        float v0 = acc2[m][0][r] + bias20;
        float v1 = acc2[m][1][r] + bias21;
        sj0 += v0 > 0.0f ? v0 : 0.0f;
        sj1 += v1 > 0.0f ? v1 : 0.0f;
      }
  }
#pragma unroll
  for (int m = 16; m <= 32; m <<= 1) {
    sj0 += __shfl_xor(sj0, m, 64);
    sj1 += __shfl_xor(sj1, m, 64);
  }
  if (ks == 0) {
    atomicAdd(&sacc[g * 256 + (2 * w + 0) * 16 + cl], sj0);
    atomicAdd(&sacc[g * 256 + (2 * w + 1) * 16 + cl], sj1);
  }
}

// ---------------------------------------------------------------------------
// Kernel 4: pooledT[g][o] = (sacc[g] . W3[:,o]) / 2048 + b3[o]   (fp32)
// ---------------------------------------------------------------------------
__global__ __launch_bounds__(96) void pool_w3(
    const float* __restrict__ sacc, const float* __restrict__ W3,
    const float* __restrict__ b3, float* __restrict__ pooledT)
{
  int gid = blockIdx.x * 96 + threadIdx.x;
  if (gid >= NGRAPH * 9) return;
  int g = gid / 9, o = gid % 9;
  float acc = 0.0f;
  const float* sp = sacc + g * 256;
#pragma unroll 8
  for (int k = 0; k < 256; ++k) acc = fmaf(sp[k], W3[k * 9 + o], acc);
  pooledT[gid] = fmaf(acc, 1.0f / (float)MPTS, b3[o]);
}

// ---------------------------------------------------------------------------
// Kernel 5: out[n,k] = sum_d pos[n,d] * pooledT[batch[n]][d*3+k]
// ---------------------------------------------------------------------------
__global__ __launch_bounds__(256) void finalize(
    const float* __restrict__ pos, const int* __restrict__ batch,
    const float* __restrict__ pooledT, float* __restrict__ out)
{
  int n = blockIdx.x * 256 + threadIdx.x;
  if (n >= NPTS) return;
  int bb = batch[n];
  float px = pos[n * 3], py = pos[n * 3 + 1], pz = pos[n * 3 + 2];
  const float* P = pooledT + bb * 9;
#pragma unroll
  for (int k2 = 0; k2 < 3; ++k2)
    out[n * 3 + k2] = fmaf(px, P[k2], fmaf(py, P[3 + k2], pz * P[6 + k2]));
}

extern "C" void kernel_launch(void* const* d_in, const int* in_sizes, int n_in,
                              void* d_out, int out_size, void* d_ws, size_t ws_size,
                              hipStream_t stream) {
  const float* pos  = (const float*)d_in[0];
  const int*   batch = (const int*)d_in[1];
  const float* W1 = (const float*)d_in[3];
  const float* b1 = (const float*)d_in[4];
  const float* W2 = (const float*)d_in[5];
  const float* b2 = (const float*)d_in[6];
  const float* W3 = (const float*)d_in[7];
  const float* b3 = (const float*)d_in[8];

  char* ws = (char*)d_ws;                      // needs ~13.0 MiB
  unsigned short* featp = (unsigned short*)(ws + FEATP_OFF);
  unsigned short* w1p   = (unsigned short*)(ws + W1P_OFF);
  unsigned short* w2p   = (unsigned short*)(ws + W2P_OFF);
  float*          sacc  = (float*)(ws + SACC_OFF);
  float*          pooledT = (float*)(ws + POOLT_OFF);
  unsigned*       zkeysG = (unsigned*)(ws + ZKEY_OFF);
  float*          out = (float*)d_out;

  prep<<<dim3(752), dim3(512), 0, stream>>>(pos, W1, W2, zkeysG, w1p, w2p, sacc);
  knn_feat<<<dim3(1024), dim3(512), 0, stream>>>(pos, zkeysG, featp);
  mlp_fused<<<dim3(1024), dim3(512), 0, stream>>>(featp, w1p, w2p, b1, b2, sacc);
  pool_w3<<<dim3(3), dim3(96), 0, stream>>>(sacc, W3, b3, pooledT);
  finalize<<<dim3(256), dim3(256), 0, stream>>>(pos, batch, pooledT, out);
}

// Round 13
// 125.809 us; speedup vs baseline: 1.1983x; 1.0769x over previous
//
#include <hip/hip_runtime.h>
#include <stdint.h>

// Problem constants (fixed by setup_inputs)
#define NPTS   65536
#define MPTS   2048
#define NGRAPH 32

typedef short s16x8 __attribute__((ext_vector_type(8)));
typedef float f32x4 __attribute__((ext_vector_type(4)));

// ws layout (bytes)
#define FEATP_OFF 0u            // 4096 ptiles * 3 ktiles * 1024B = 12582912
#define W1P_OFF   12582912u     // 96*1024*2   = 196608
#define W2P_OFF   12779520u     // 1024*256*2  = 524288
#define SACC_OFF  13303808u     // 32*256*4    = 32768  (per-graph sum of h2)
#define ZKEY_OFF  13337728u     // 32*2048*4   = 262144 (total 13599872 B)

#define PAD  128                // sentinel pad on each side of z-sorted array
#define ZN   (MPTS + 2 * PAD)   // 2304

__device__ __forceinline__ unsigned short f2bf(float f) {
  unsigned u = __float_as_uint(f);
  u = (u + 0x7FFFu + ((u >> 16) & 1u)) >> 16;   // RNE
  return (unsigned short)u;
}

// u32 compare-exchange: v_min_u32 + v_max_u32 (2 VALU, no vcc).
__device__ __forceinline__ void ce32(unsigned& a, unsigned& b) {
  unsigned lo = __builtin_elementwise_min(a, b);
  b = __builtin_elementwise_max(a, b);
  a = lo;
}

// Batcher odd-even mergesort, ascending, fully unrolled (N=8: 19 CEs).
template <int N>
__device__ __forceinline__ void sortN(unsigned* k) {
#pragma unroll
  for (int p = 1; p < N; p <<= 1)
#pragma unroll
    for (int q = p; q >= 1; q >>= 1)
#pragma unroll
      for (int j = q % p; j + q < N; j += 2 * q)
#pragma unroll
        for (int i = 0; i < q; ++i)
          if (i + j + q < N)
            if ((i + j) / (2 * p) == (i + j + q) / (2 * p))
              ce32(k[i + j], k[i + j + q]);
}

// r,b sorted asc. r <- lowest 8 of r ∪ b, sorted asc. 8 min + 12 CE.
__device__ __forceinline__ void mergelow8(unsigned r[8], const unsigned b[8]) {
#pragma unroll
  for (int i = 0; i < 8; ++i)
    r[i] = __builtin_elementwise_min(r[i], b[7 - i]);
#pragma unroll
  for (int d = 4; d >= 1; d >>= 1)
#pragma unroll
    for (int i = 0; i < 8; ++i)
      if ((i & d) == 0) ce32(r[i], r[i + d]);
}

// r,b sorted asc (16 each). r <- lowest 16, sorted. 16 min + 32 CE.
__device__ __forceinline__ void mergelow16(unsigned r[16], const unsigned b[16]) {
#pragma unroll
  for (int i = 0; i < 16; ++i)
    r[i] = __builtin_elementwise_min(r[i], b[15 - i]);
#pragma unroll
  for (int d = 8; d >= 1; d >>= 1)
#pragma unroll
    for (int i = 0; i < 16; ++i)
      if ((i & d) == 0) ce32(r[i], r[i + d]);
}

// ---------------------------------------------------------------------------
// Kernel 1 (prep): blocks 0..31 z-sort one graph each (hierarchical bitonic:
// shfl for j<=32, in-thread slots for j in {64,128}, LDS only for j>=256);
// blocks 32.. pack W1/W2 into MFMA fragment-linear bf16 tiles, zero sacc.
// ---------------------------------------------------------------------------
__global__ __launch_bounds__(512) void prep(
    const float* __restrict__ pos, const float* __restrict__ W1,
    const float* __restrict__ W2, unsigned* __restrict__ zkeysG,
    unsigned short* __restrict__ w1p, unsigned short* __restrict__ w2p,
    float* __restrict__ sacc)
{
  __shared__ unsigned sk[MPTS];
  int b = blockIdx.x;
  int tid = threadIdx.x;
  if (b < NGRAPH) {
    const float* gp = pos + (size_t)b * MPTS * 3;
    int w = tid >> 6, l = tid & 63;
    unsigned v[4];
#pragma unroll
    for (int s = 0; s < 4; ++s) {
      int i = w * 256 + s * 64 + l;
      unsigned u = __float_as_uint(gp[i * 3 + 2]);
      u ^= ((unsigned)(((int)u) >> 31)) | 0x80000000u;   // monotone fold
      v[s] = (u & 0xFFFFF800u) | (unsigned)i;
    }
#pragma unroll
    for (int kk = 1; kk <= 11; ++kk) {
      const int k2 = 1 << kk;
      // LDS stages: j in {1024, 512, 256} (cross-wave)
      if (k2 >= 512) {
        __syncthreads();                       // protect sk vs prior loads
#pragma unroll
        for (int s = 0; s < 4; ++s) sk[w * 256 + s * 64 + l] = v[s];
#pragma unroll
        for (int j = k2 >> 1; j >= 256; j >>= 1) {
          __syncthreads();
#pragma unroll
          for (int e = 0; e < 4; ++e) {
            int i = tid + (e << 9);
            int ix = i ^ j;
            if (ix > i) {
              unsigned a = sk[i], b2 = sk[ix];
              bool up = ((i & k2) == 0);
              unsigned lo = __builtin_elementwise_min(a, b2);
              unsigned hi = __builtin_elementwise_max(a, b2);
              sk[i] = up ? lo : hi;
              sk[ix] = up ? hi : lo;
            }
          }
        }
        __syncthreads();
#pragma unroll
        for (int s = 0; s < 4; ++s) v[s] = sk[w * 256 + s * 64 + l];
      }
      // in-thread slot stages: j = 128 (s^2), 64 (s^1)
#pragma unroll
      for (int j = 128; j >= 64; j >>= 1) {
        if (k2 > j) {
          int sd = j >> 6;
#pragma unroll
          for (int s = 0; s < 4; ++s) {
            int sp = s ^ sd;
            if (sp > s) {
              bool up = (((w * 256 + s * 64 + l) & k2) == 0);
              unsigned lo = __builtin_elementwise_min(v[s], v[sp]);
              unsigned hi = __builtin_elementwise_max(v[s], v[sp]);
              v[s] = up ? lo : hi;
              v[sp] = up ? hi : lo;
            }
          }
        }
      }
      // shfl stages: j = 32..1 (in-wave, no barriers)
#pragma unroll
      for (int j = 32; j >= 1; j >>= 1) {
        if (k2 > j) {
#pragma unroll
          for (int s = 0; s < 4; ++s) {
            unsigned p = __shfl_xor(v[s], j, 64);
            bool up = (((w * 256 + s * 64 + l) & k2) == 0);
            bool lower = ((l & j) == 0);
            v[s] = (lower == up) ? __builtin_elementwise_min(v[s], p)
                                 : __builtin_elementwise_max(v[s], p);
          }
        }
      }
    }
#pragma unroll
    for (int s = 0; s < 4; ++s)
      zkeysG[(b << 11) + w * 256 + s * 64 + l] = v[s];
  } else {
    int pid = (b - NGRAPH) * 512 + tid;
    if (pid < 98304) {                          // W1: 96 x 1024
      int k = pid >> 10, n = pid & 1023;
      int kt = k >> 5, h = (k >> 3) & 3, j = k & 7;
      int nt = n >> 4, cc = n & 15;
      w1p[((size_t)(kt * 64 + nt) * 64 + h * 16 + cc) * 8 + j] = f2bf(W1[pid]);
    } else if (pid < 98304 + 262144) {          // W2: 1024 x 256
      int t = pid - 98304;
      int k = t >> 8, n = t & 255;
      int kt = k >> 5, h = (k >> 3) & 3, j = k & 7;
      int nt = n >> 4, cc = n & 15;
      w2p[((size_t)(kt * 16 + nt) * 64 + h * 16 + cc) * 8 + j] = f2bf(W2[t]);
    } else if (pid < 360448 + 8192) {           // zero per-graph h2 sums
      sacc[pid - 360448] = 0.0f;
    }
  }
}

// ---------------------------------------------------------------------------
// Kernel 2 (v8 — round-10 source, skip REVERTED): wave-shared z-window 16-NN.
// Spread rank-group map for load balance; tight pigeonhole bound
// B = max8(run[1]); inf-sentinel padding; frontier prefetch. The r11 "skip"
// is removed: it cost 24 VGPR (k[16] live across the branch) -> occupancy
// 43% -> 26% and a net +6.6 us (r12 counters).
// ---------------------------------------------------------------------------
__global__ __launch_bounds__(512, 4) void knn_feat(
    const float* __restrict__ pos, const unsigned* __restrict__ zkeysG,
    unsigned short* __restrict__ featp)
{
  __shared__ float4 zq[ZN];
  const float INF = __uint_as_float(0x7F800000u);
  int g = blockIdx.x >> 5;
  const float* gp = pos + (size_t)g * MPTS * 3;
  for (int i = threadIdx.x; i < ZN; i += 512) {
    float4 v;
    if (i < PAD) v = make_float4(INF, INF, -INF, INF);          // left: z=-inf
    else if (i >= MPTS + PAD) v = make_float4(INF, INF, INF, INF);
    else {
      int o = (int)(zkeysG[(g << 11) + (i - PAD)] & 0x7FFu);
      float x = gp[o * 3], y = gp[o * 3 + 1], z = gp[o * 3 + 2];
      v = make_float4(x, y, z, fmaf(x, x, fmaf(y, y, z * z)));
    }
    zq[i] = v;
  }
  __syncthreads();

  int l = threadIdx.x & 63, w = threadIdx.x >> 6;
  int qv = l & 7, t = l >> 3;
  int R0 = ((w << 5) | (blockIdx.x & 31)) << 3;    // spread rank-group map
  int R = R0 + qv;                                 // this lane's query rank
  float4 c = zq[R + PAD];
  float cs = c.w, cz = c.z;
  float zc = 0.5f * (zq[R0 + PAD].z + zq[R0 + PAD + 7].z);   // wave z center

  unsigned run[8];
#pragma unroll
  for (int i = 0; i < 8; ++i) run[i] = 0xFFFFFFFFu;
  unsigned B = 0xFFFFFFFFu;                        // per-query d16 upper bound

  int LO = R0 + PAD, HI = R0 + PAD;                // scanned = [LO, HI)
  float zl = zq[LO - 1].z, zr = zq[HI].z;          // frontier (prefetched)

  for (int step = 0; step < 18; ++step) {
    bool canL = (LO >= PAD), canR = (HI + PAD <= ZN);
    unsigned thr = (B > 0xFFFEFFFFu) ? 0xFFFFFFFFu : B + 0x10000u;
    float dl = cz - zl, dr = zr - cz;
    bool doneL = !canL || ((__float_as_uint(dl * dl) & 0xFFFFF800u) > thr);
    bool doneR = !canR || ((__float_as_uint(dr * dr) & 0xFFFFF800u) > thr);
    if (__all(doneL && doneR)) break;

    bool goR = canR && (!canL || ((zr - zc) <= (zc - zl)));    // uniform
    int base = goR ? HI : LO - PAD;
    if (goR) HI += PAD; else LO -= PAD;

    // prefetch next frontier (latency hides under the candidate block)
    zl = (LO >= 1) ? zq[LO - 1].z : -INF;
    zr = (HI < ZN) ? zq[HI].z : INF;

    int bt = base + t;
    unsigned k[16];
#pragma unroll
    for (int i = 0; i < 16; ++i) {
      int p = bt + (i << 3);
      float4 P = zq[p];
      float dot = fmaf(c.x, P.x, fmaf(c.y, P.y, c.z * P.z));
      float d2 = fmaf(-2.0f, dot, cs + P.w);       // == 0 exactly for self
      k[i] = (__float_as_uint(d2) & 0xFFFFF800u) |
             ((unsigned)(p - PAD) & 0x7FFu);       // v_bfi pattern
    }
    sortN<8>(k); sortN<8>(k + 8);
    mergelow8(k, k + 8);          // k[0..7] = sorted lowest 8 of this batch
    mergelow8(run, k);

    // tighten B: per-query max of run[1] over the 8 segment-threads
    unsigned bb = run[1];
    bb = __builtin_elementwise_max(bb, (unsigned)__shfl_xor(bb, 8, 64));
    bb = __builtin_elementwise_max(bb, (unsigned)__shfl_xor(bb, 16, 64));
    bb = __builtin_elementwise_max(bb, (unsigned)__shfl_xor(bb, 32, 64));
    B = bb;
  }

  // cross-thread reduction over the 8 segment-threads of this query
  unsigned t16[16];
  {
    unsigned oth[8];
#pragma unroll
    for (int i = 0; i < 8; ++i) oth[i] = __shfl_xor(run[i], 8, 64);
#pragma unroll
    for (int i = 0; i < 8; ++i) {
      unsigned a = run[i], x = oth[7 - i];
      t16[i]     = __builtin_elementwise_min(a, x);
      t16[i + 8] = __builtin_elementwise_max(a, x);
    }
#pragma unroll
    for (int d = 4; d >= 1; d >>= 1)
#pragma unroll
      for (int i = 0; i < 16; ++i)
        if ((i & d) == 0) ce32(t16[i], t16[i + d]);   // stays within halves
  }
#pragma unroll
  for (int m = 16; m <= 32; m <<= 1) {
    unsigned o2[16];
#pragma unroll
    for (int i = 0; i < 16; ++i) o2[i] = __shfl_xor(t16[i], m, 64);
    mergelow16(t16, o2);
  }

  // feature emission: lanes t==0 (l = 0..7), consecutive z-ranks -> coalesced
  if (t == 0) {
    float nx[16], ny[16], nz[16];
#pragma unroll
    for (int i = 0; i < 16; ++i) {
      int rk = (int)(t16[i] & 0x7FFu);
      float4 p = zq[rk + PAD];
      nx[i] = p.x; ny[i] = p.y; nz[i] = p.z;
    }
    int n = g * MPTS + R;                        // z-rank order (mean-invariant)
    unsigned short* op = featp + (size_t)(n >> 4) * 1536 + (size_t)(n & 15) * 8;
#pragma unroll
    for (int kt = 0; kt < 3; ++kt) {
#pragma unroll
      for (int h = 0; h < 4; ++h) {
        s16x8 v;
#pragma unroll
        for (int j = 0; j < 8; ++j) {
          int f = kt * 32 + h * 8 + j;
          int kn = f / 6, comp = f % 6;        // compile-time after unroll
          float val;
          if      (comp == 0) val = c.x;
          else if (comp == 1) val = c.y;
          else if (comp == 2) val = c.z;
          else if (comp == 3) val = c.x - nx[kn];
          else if (comp == 4) val = c.y - ny[kn];
          else                val = c.z - nz[kn];
          v[j] = (short)f2bf(val);
        }
        *(s16x8*)(op + kt * 512 + h * 128) = v;
      }
    }
  }
}

// --- mlp helpers: C-array references so everything inlines to registers ----
__device__ __forceinline__ void load_b1(s16x8 (&dst)[3],
    const unsigned short* __restrict__ w1p, int nt, int lane) {
#pragma unroll
  for (int kt = 0; kt < 3; ++kt)
    dst[kt] = *(const s16x8*)(w1p + ((size_t)(kt * 64 + nt) * 64 + lane) * 8);
}

__device__ __forceinline__ void load_b2(s16x8 (&dst)[8],
    const unsigned short* __restrict__ w2p, int c, int w, int lane) {
#pragma unroll
  for (int kt2 = 0; kt2 < 4; ++kt2)
#pragma unroll
    for (int j = 0; j < 2; ++j)
      dst[kt2 * 2 + j] = *(const s16x8*)(
          w2p + ((size_t)((c * 4 + kt2) * 16 + (w * 2 + j)) * 64 + lane) * 8);
}

__device__ __forceinline__ void gemm1_step(const s16x8 (&a1)[4][3],
    const s16x8 (&b1f)[3], float bias1,
    unsigned short (*h1buf)[136], int w, int cl, int ks) {
#pragma unroll
  for (int m = 0; m < 4; ++m) {
    f32x4 acc1 = (f32x4){0, 0, 0, 0};
#pragma unroll
    for (int kt = 0; kt < 3; ++kt)
      acc1 = __builtin_amdgcn_mfma_f32_16x16x32_bf16(a1[m][kt], b1f[kt], acc1, 0, 0, 0);
#pragma unroll
    for (int r = 0; r < 4; ++r) {
      float v = acc1[r] + bias1;
      v = v > 0.0f ? v : 0.0f;
      h1buf[m * 16 + ks * 4 + r][w * 16 + cl] = f2bf(v);
    }
  }
}

__device__ __forceinline__ void gemm2_step(const s16x8 (&b2f)[8],
    f32x4 (&acc2)[4][2], const unsigned short (*h1buf)[136], int cl, int ks) {
#pragma unroll
  for (int kt2 = 0; kt2 < 4; ++kt2) {
    s16x8 afr[4];
#pragma unroll
    for (int m = 0; m < 4; ++m)
      afr[m] = *(const s16x8*)&h1buf[m * 16 + cl][kt2 * 32 + ks * 8];
#pragma unroll
    for (int j = 0; j < 2; ++j)
#pragma unroll
      for (int m = 0; m < 4; ++m)
        acc2[m][j] = __builtin_amdgcn_mfma_f32_16x16x32_bf16(
            afr[m], b2f[kt2 * 2 + j], acc2[m][j], 0, 0, 0);
  }
}

// ---------------------------------------------------------------------------
// Kernel 3 (v5, unchanged from round 12): fused MLP with chunk-ahead B2
// ping-pong; (512,2) — no spill.
// ---------------------------------------------------------------------------
__global__ __launch_bounds__(512, 2) void mlp_fused(
    const unsigned short* __restrict__ featp,
    const unsigned short* __restrict__ w1p,
    const unsigned short* __restrict__ w2p,
    const float* __restrict__ b1, const float* __restrict__ b2,
    float* __restrict__ sacc)
{
  __shared__ unsigned short h1c[2][64][136];  // 2 x 17408 B, rows 16B-aligned

  int tid = threadIdx.x;
  int w = tid >> 6, lane = tid & 63;
  int b = blockIdx.x;
  int g = b >> 5;                             // 32 blocks per graph
  int ks = lane >> 4;                         // k-slot / C row-group
  int cl = lane & 15;

  // persistent A fragments: all 4 m-tiles x 3 k-tiles (48 VGPR)
  s16x8 a1[4][3];
#pragma unroll
  for (int m = 0; m < 4; ++m) {
    const unsigned short* ap = featp + (size_t)(b * 4 + m) * 1536 + (size_t)lane * 8;
#pragma unroll
    for (int kt = 0; kt < 3; ++kt) a1[m][kt] = *(const s16x8*)(ap + kt * 512);
  }

  f32x4 acc2[4][2];                           // 4 m-tiles x 2 n2-tiles
#pragma unroll
  for (int m = 0; m < 4; ++m) {
    acc2[m][0] = (f32x4){0, 0, 0, 0};
    acc2[m][1] = (f32x4){0, 0, 0, 0};
  }

  // all 8 chunk biases up front (8 VGPR)
  float bias1v[8];
#pragma unroll
  for (int c = 0; c < 8; ++c) bias1v[c] = b1[(c * 8 + w) * 16 + cl];

  s16x8 b1f[3];
  load_b1(b1f, w1p, w, lane);                 // chunk 0: nt = w
  s16x8 b2a[8], b2b[8];
  load_b2(b2a, w2p, 0, w, lane);              // chunk 0 B2

#pragma unroll
  for (int cc = 0; cc < 8; cc += 2) {
    // ---- even chunk cc -> buf 0 ----
    gemm1_step(a1, b1f, bias1v[cc], h1c[0], w, cl, ks);
    load_b1(b1f, w1p, (cc + 1) * 8 + w, lane);          // b1 for cc+1
    __syncthreads();
    load_b2(b2b, w2p, cc + 1, w, lane);                 // issue early: lands
    gemm2_step(b2a, acc2, h1c[0], cl, ks);              //   during these MFMAs

    // ---- odd chunk cc+1 -> buf 1 ----
    gemm1_step(a1, b1f, bias1v[cc + 1], h1c[1], w, cl, ks);
    if (cc + 2 < 8) load_b1(b1f, w1p, (cc + 2) * 8 + w, lane);
    __syncthreads();
    if (cc + 2 < 8) load_b2(b2a, w2p, cc + 2, w, lane);
    gemm2_step(b2b, acc2, h1c[1], cl, ks);
  }

  // ---- h2 = relu(acc2 + b2); sum over this block's 64 points ----
  float sj0 = 0.0f, sj1 = 0.0f;
  {
    float bias20 = b2[(2 * w + 0) * 16 + cl];
    float bias21 = b2[(2 * w + 1) * 16 + cl];
#pragma unroll
    for (int m = 0; m < 4; ++m)
#pragma unroll
      for (int r = 0; r < 4; ++r) {
        float v0 = acc2[m][0][r] + bias20;
        float v1 = acc2[m][1][r] + bias21;
        sj0 += v0 > 0.0f ? v0 : 0.0f;
        sj1 += v1 > 0.0f ? v1 : 0.0f;
      }
  }
#pragma unroll
  for (int m = 16; m <= 32; m <<= 1) {
    sj0 += __shfl_xor(sj0, m, 64);
    sj1 += __shfl_xor(sj1, m, 64);
  }
  if (ks == 0) {
    atomicAdd(&sacc[g * 256 + (2 * w + 0) * 16 + cl], sj0);
    atomicAdd(&sacc[g * 256 + (2 * w + 1) * 16 + cl], sj1);
  }
}

// ---------------------------------------------------------------------------
// Kernel 4 (fused pool+finalize): block b covers points n in [b*256,b*256+256)
// — all in graph g = b>>3. Threads 0..8 recompute this graph's 9 pooled
// values from sacc (same fmaf order as the old pool_w3 -> bit-identical),
// then all threads apply the 3x3 transform.
// ---------------------------------------------------------------------------
__global__ __launch_bounds__(256) void finalize(
    const float* __restrict__ pos, const float* __restrict__ sacc,
    const float* __restrict__ W3, const float* __restrict__ b3,
    float* __restrict__ out)
{
  __shared__ float P[9];
  int b = blockIdx.x;
  int g = b >> 3;                              // 8 blocks per graph
  int tid = threadIdx.x;
  if (tid < 9) {
    float acc = 0.0f;
    const float* sp = sacc + g * 256;
#pragma unroll 8
    for (int k = 0; k < 256; ++k) acc = fmaf(sp[k], W3[k * 9 + tid], acc);
    P[tid] = fmaf(acc, 1.0f / (float)MPTS, b3[tid]);
  }
  __syncthreads();
  int n = b * 256 + tid;
  float px = pos[n * 3], py = pos[n * 3 + 1], pz = pos[n * 3 + 2];
#pragma unroll
  for (int k2 = 0; k2 < 3; ++k2)
    out[n * 3 + k2] = fmaf(px, P[k2], fmaf(py, P[3 + k2], pz * P[6 + k2]));
}

extern "C" void kernel_launch(void* const* d_in, const int* in_sizes, int n_in,
                              void* d_out, int out_size, void* d_ws, size_t ws_size,
                              hipStream_t stream) {
  const float* pos  = (const float*)d_in[0];
  const float* W1 = (const float*)d_in[3];
  const float* b1 = (const float*)d_in[4];
  const float* W2 = (const float*)d_in[5];
  const float* b2 = (const float*)d_in[6];
  const float* W3 = (const float*)d_in[7];
  const float* b3 = (const float*)d_in[8];

  char* ws = (char*)d_ws;                      // needs ~13.0 MiB
  unsigned short* featp = (unsigned short*)(ws + FEATP_OFF);
  unsigned short* w1p   = (unsigned short*)(ws + W1P_OFF);
  unsigned short* w2p   = (unsigned short*)(ws + W2P_OFF);
  float*          sacc  = (float*)(ws + SACC_OFF);
  unsigned*       zkeysG = (unsigned*)(ws + ZKEY_OFF);
  float*          out = (float*)d_out;

  prep<<<dim3(752), dim3(512), 0, stream>>>(pos, W1, W2, zkeysG, w1p, w2p, sacc);
  knn_feat<<<dim3(1024), dim3(512), 0, stream>>>(pos, zkeysG, featp);
  mlp_fused<<<dim3(1024), dim3(512), 0, stream>>>(featp, w1p, w2p, b1, b2, sacc);
  finalize<<<dim3(256), dim3(256), 0, stream>>>(pos, sacc, W3, b3, out);
}